// Round 2
// baseline (491.373 us; speedup 1.0000x reference)
//
#include <hip/hip_runtime.h>
#include <hip/hip_bf16.h>
#include <cstdint>
#include <cstddef>

typedef __bf16 bf16_t;
typedef bf16_t bf16x8 __attribute__((ext_vector_type(8)));
typedef bf16_t bf16x4 __attribute__((ext_vector_type(4)));
typedef float f32x4 __attribute__((ext_vector_type(4)));

#define NB 8
#define NT 1024
#define NC 1024
#define NH 16
#define ND 64
#define NTP 64

// ---------------- cast fp32 -> bf16 (vectorized x4) ----------------
__global__ __launch_bounds__(256) void k_cast_bf16(const float* __restrict__ src,
                                                   bf16_t* __restrict__ dst, int n4) {
    int i = blockIdx.x * 256 + threadIdx.x;
    if (i < n4) {
        float4 f = ((const float4*)src)[i];
        bf16x4 o;
        o[0] = (bf16_t)f.x; o[1] = (bf16_t)f.y; o[2] = (bf16_t)f.z; o[3] = (bf16_t)f.w;
        ((bf16x4*)dst)[i] = o;
    }
}

// ---------------- transpose + cast: src (K,N) fp32 -> dst (N,K) bf16 ----------------
__global__ __launch_bounds__(256) void k_transpose_cast(const float* __restrict__ src,
                                                        bf16_t* __restrict__ dst,
                                                        int K, int N) {
    __shared__ float tile[32][33];
    int nt = blockIdx.x, kt = blockIdx.y;
    int tx = threadIdx.x & 31;
    int ty = threadIdx.x >> 5;  // 0..7
#pragma unroll
    for (int i = 0; i < 4; i++) {
        int r = ty + i * 8;
        tile[r][tx] = src[(size_t)(kt * 32 + r) * N + nt * 32 + tx];
    }
    __syncthreads();
#pragma unroll
    for (int i = 0; i < 4; i++) {
        int r = ty + i * 8;
        dst[(size_t)(nt * 32 + r) * K + kt * 32 + tx] = (bf16_t)tile[tx][r];
    }
}

// ---------------- per-head V transpose: qkv v-slab -> vT (b,h,d,T) bf16 ----------------
// src rows: b*T + t (stride 3072), v element col = 2*NC + h*64 + d
// grid: (T/32, ND/32, NB*NH), block 256
__global__ __launch_bounds__(256) void k_vT(const bf16_t* __restrict__ src,
                                            bf16_t* __restrict__ dst, int T) {
    __shared__ bf16_t tile[32][33];
    const int bh = blockIdx.z;
    const int b = bh >> 4, h = bh & 15;
    const int t0 = blockIdx.x * 32, d0 = blockIdx.y * 32;
    const int tx = threadIdx.x & 31;
    const int ty = threadIdx.x >> 5;  // 0..7
#pragma unroll
    for (int i = 0; i < 4; i++) {
        int r = ty + i * 8;  // t offset
        tile[r][tx] = src[(size_t)(b * T + t0 + r) * 3072 + 2 * NC + h * 64 + d0 + tx];
    }
    __syncthreads();
#pragma unroll
    for (int i = 0; i < 4; i++) {
        int r = ty + i * 8;  // d offset
        dst[((size_t)bh * ND + d0 + r) * T + t0 + tx] = tile[tx][r];
    }
}

// ---------------- GEMM: C(M,N) = A(M,K) @ BT(N,K)^T + bias ----------------
template <bool OUT_F32>
__global__ __launch_bounds__(256) void k_gemm_bt(const bf16_t* __restrict__ A,
                                                 const bf16_t* __restrict__ BT,
                                                 const float* __restrict__ bias,
                                                 void* __restrict__ Cout,
                                                 int M, int N, int K) {
    __shared__ bf16_t As[128 * 72];
    __shared__ bf16_t Bs[128 * 72];
    const int tid = threadIdx.x;
    const int lane = tid & 63;
    const int wave = tid >> 6;
    const int quad = lane >> 4;
    const int l15 = lane & 15;
    const int wm = (wave >> 1) * 64;
    const int wn = (wave & 1) * 64;
    const size_t rowA0 = (size_t)blockIdx.y * 128;
    const size_t colB0 = (size_t)blockIdx.x * 128;

    const f32x4 fz = {0.f, 0.f, 0.f, 0.f};
    f32x4 acc[4][4];
#pragma unroll
    for (int i = 0; i < 4; i++)
#pragma unroll
        for (int j = 0; j < 4; j++) acc[i][j] = fz;

    for (int k0 = 0; k0 < K; k0 += 64) {
        __syncthreads();
#pragma unroll
        for (int i = 0; i < 4; i++) {
            int c = tid + i * 256;
            int r = c >> 3;
            int kc = (c & 7) * 8;
            uint4 av = *(const uint4*)(A + (rowA0 + r) * K + k0 + kc);
            *(uint4*)(&As[r * 72 + kc]) = av;
            uint4 bv = *(const uint4*)(BT + (colB0 + r) * K + k0 + kc);
            *(uint4*)(&Bs[r * 72 + kc]) = bv;
        }
        __syncthreads();
#pragma unroll
        for (int kk = 0; kk < 2; kk++) {
            bf16x8 af[4], bfr[4];
#pragma unroll
            for (int i = 0; i < 4; i++)
                af[i] = *(const bf16x8*)(&As[(wm + i * 16 + l15) * 72 + kk * 32 + quad * 8]);
#pragma unroll
            for (int j = 0; j < 4; j++)
                bfr[j] = *(const bf16x8*)(&Bs[(wn + j * 16 + l15) * 72 + kk * 32 + quad * 8]);
#pragma unroll
            for (int i = 0; i < 4; i++)
#pragma unroll
                for (int j = 0; j < 4; j++)
                    acc[i][j] = __builtin_amdgcn_mfma_f32_16x16x32_bf16(af[i], bfr[j], acc[i][j], 0, 0, 0);
        }
    }
#pragma unroll
    for (int i = 0; i < 4; i++) {
        size_t row = rowA0 + wm + i * 16 + quad * 4;
#pragma unroll
        for (int j = 0; j < 4; j++) {
            int col = (int)colB0 + wn + j * 16 + l15;
            float bv = bias[col];
#pragma unroll
            for (int r = 0; r < 4; r++) {
                float v = acc[i][j][r] + bv;
                if (OUT_F32)
                    ((float*)Cout)[(row + r) * (size_t)N + col] = v;
                else
                    ((bf16_t*)Cout)[(row + r) * (size_t)N + col] = (bf16_t)v;
            }
        }
    }
}

// ---------------- fused dual-softmax causal attention, zero-barrier ----------------
// One block per (q-tile 64, head, batch); each wave independently owns 16 q-rows.
// K and V^T MFMA B-fragments loaded straight from global (L1/L2 shared across the
// block's 4 waves). P layout transform via wave-private LDS scratch (no barriers).
__global__ __launch_bounds__(256) void k_attn2(const bf16_t* __restrict__ qkv,
                                               const bf16_t* __restrict__ pqkv,
                                               const bf16_t* __restrict__ vT,
                                               const bf16_t* __restrict__ pvT,
                                               bf16_t* __restrict__ y) {
    const int qt = blockIdx.x;
    const int h = blockIdx.y;
    const int b = blockIdx.z;

    __shared__ bf16_t Ps[4][16 * 72];  // per-wave P scratch

    const int tid = threadIdx.x;
    const int lane = tid & 63;
    const int wave = tid >> 6;
    const int quad = lane >> 4;
    const int l15 = lane & 15;
    const float scale = 0.125f;  // 1/sqrt(64)

    const size_t qrow0 = (size_t)b * NT + (size_t)qt * 64 + wave * 16;  // this wave's first q row

    // Q A-fragments, loaded once (rows l15 within wave's 16)
    bf16x8 aq0 = *(const bf16x8*)(qkv + (qrow0 + l15) * 3072 + h * 64 + quad * 8);
    bf16x8 aq1 = *(const bf16x8*)(qkv + (qrow0 + l15) * 3072 + h * 64 + 32 + quad * 8);

    const f32x4 fz = {0.f, 0.f, 0.f, 0.f};
    bf16_t* P = Ps[wave];

    auto process = [&](const bf16_t* Krow0, int kcol0, const bf16_t* VTtile, int vstride,
                       bool diagMask, float* mr, float* lr, f32x4* O) {
        // ---- S = Q @ K^T (16 q-rows x 64 keys) ----
        bf16x8 bk[2][4];
#pragma unroll
        for (int kk = 0; kk < 2; kk++)
#pragma unroll
            for (int j = 0; j < 4; j++)
                bk[kk][j] = *(const bf16x8*)(Krow0 + (size_t)(j * 16 + l15) * 3072 + kcol0 + kk * 32 + quad * 8);
        f32x4 S[4];
#pragma unroll
        for (int j = 0; j < 4; j++) S[j] = fz;
#pragma unroll
        for (int j = 0; j < 4; j++) {
            S[j] = __builtin_amdgcn_mfma_f32_16x16x32_bf16(aq0, bk[0][j], S[j], 0, 0, 0);
            S[j] = __builtin_amdgcn_mfma_f32_16x16x32_bf16(aq1, bk[1][j], S[j], 0, 0, 0);
        }
        // prefetch V^T B-fragments while softmax runs
        bf16x8 bv[2][4];
#pragma unroll
        for (int kk = 0; kk < 2; kk++)
#pragma unroll
            for (int dj = 0; dj < 4; dj++)
                bv[kk][dj] = *(const bf16x8*)(VTtile + (size_t)(dj * 16 + l15) * vstride + kk * 32 + quad * 8);
        // ---- softmax (rows quad*4+r, cols j*16+l15) ----
        float rmax[4];
#pragma unroll
        for (int r = 0; r < 4; r++) rmax[r] = -1e30f;
#pragma unroll
        for (int j = 0; j < 4; j++) {
            int n = j * 16 + l15;
#pragma unroll
            for (int r = 0; r < 4; r++) {
                float s = S[j][r] * scale;
                int m = wave * 16 + quad * 4 + r;
                if (diagMask && n > m) s = -1e30f;
                S[j][r] = s;
                rmax[r] = fmaxf(rmax[r], s);
            }
        }
#pragma unroll
        for (int r = 0; r < 4; r++) {
            float v = rmax[r];
#pragma unroll
            for (int off = 1; off < 16; off <<= 1) v = fmaxf(v, __shfl_xor(v, off, 64));
            rmax[r] = v;
        }
        float alpha[4];
#pragma unroll
        for (int r = 0; r < 4; r++) {
            float mn = fmaxf(mr[r], rmax[r]);
            alpha[r] = __expf(mr[r] - mn);
            mr[r] = mn;
        }
        float rsum[4] = {0.f, 0.f, 0.f, 0.f};
#pragma unroll
        for (int j = 0; j < 4; j++) {
#pragma unroll
            for (int r = 0; r < 4; r++) {
                float p = __expf(S[j][r] - mr[r]);
                S[j][r] = p;
                rsum[r] += p;
            }
        }
#pragma unroll
        for (int r = 0; r < 4; r++) {
            float v = rsum[r];
#pragma unroll
            for (int off = 1; off < 16; off <<= 1) v += __shfl_xor(v, off, 64);
            lr[r] = lr[r] * alpha[r] + v;
        }
        // ---- P: C-layout -> A-layout via wave-private LDS (wave-synchronous) ----
#pragma unroll
        for (int j = 0; j < 4; j++)
#pragma unroll
            for (int r = 0; r < 4; r++)
                P[(quad * 4 + r) * 72 + j * 16 + l15] = (bf16_t)S[j][r];
        __builtin_amdgcn_s_waitcnt(0xc07f);  // lgkmcnt(0)
        __builtin_amdgcn_wave_barrier();
        bf16x8 ap0 = *(const bf16x8*)(&P[l15 * 72 + quad * 8]);
        bf16x8 ap1 = *(const bf16x8*)(&P[l15 * 72 + 32 + quad * 8]);
        // ---- O = O*alpha + P @ V ----
#pragma unroll
        for (int dj = 0; dj < 4; dj++)
#pragma unroll
            for (int r = 0; r < 4; r++) O[dj][r] *= alpha[r];
#pragma unroll
        for (int dj = 0; dj < 4; dj++) {
            O[dj] = __builtin_amdgcn_mfma_f32_16x16x32_bf16(ap0, bv[0][dj], O[dj], 0, 0, 0);
            O[dj] = __builtin_amdgcn_mfma_f32_16x16x32_bf16(ap1, bv[1][dj], O[dj], 0, 0, 0);
        }
    };

    // ---- main causal attention ----
    float m_m[4], l_m[4];
    f32x4 Om[4];
#pragma unroll
    for (int r = 0; r < 4; r++) { m_m[r] = -1e30f; l_m[r] = 0.f; }
#pragma unroll
    for (int dj = 0; dj < 4; dj++) Om[dj] = fz;
    {
        const bf16_t* vTh = vT + (size_t)(b * NH + h) * ND * NT;
        for (int kt = 0; kt <= qt; kt++) {
            process(qkv + (size_t)(b * NT + kt * 64) * 3072, NC + h * 64,
                    vTh + kt * 64, NT, kt == qt, m_m, l_m, Om);
        }
    }

    // ---- prefix attention (separate softmax) ----
    float m_p[4], l_p[4];
    f32x4 Op[4];
#pragma unroll
    for (int r = 0; r < 4; r++) { m_p[r] = -1e30f; l_p[r] = 0.f; }
#pragma unroll
    for (int dj = 0; dj < 4; dj++) Op[dj] = fz;
    process(pqkv + (size_t)(b * NTP) * 3072, NC + h * 64,
            pvT + (size_t)(b * NH + h) * ND * NTP, NTP, qt == 0, m_p, l_p, Op);

    // ---- combine and store ----
#pragma unroll
    for (int dj = 0; dj < 4; dj++) {
#pragma unroll
        for (int r = 0; r < 4; r++) {
            float v = Om[dj][r] / l_m[r] + Op[dj][r] / l_p[r];
            y[(qrow0 + quad * 4 + r) * NC + h * 64 + dj * 16 + l15] = (bf16_t)v;
        }
    }
}

// ---------------- launch ----------------
extern "C" void kernel_launch(void* const* d_in, const int* in_sizes, int n_in,
                              void* d_out, int out_size, void* d_ws, size_t ws_size,
                              hipStream_t stream) {
    (void)in_sizes; (void)n_in; (void)out_size; (void)ws_size;
    const float* x        = (const float*)d_in[0];
    const float* prefix   = (const float*)d_in[1];
    const float* w_attn   = (const float*)d_in[2];
    const float* b_attn   = (const float*)d_in[3];
    const float* w_prefix = (const float*)d_in[4];
    const float* b_prefix = (const float*)d_in[5];
    const float* w_proj   = (const float*)d_in[6];
    const float* b_proj   = (const float*)d_in[7];
    float* out = (float*)d_out;

    char* p = (char*)d_ws;
    auto carve = [&](size_t bytes) {
        char* q = p;
        p += (bytes + 255) & ~(size_t)255;
        return q;
    };
    bf16_t* xb   = (bf16_t*)carve((size_t)NB * NT * NC * 2);        // 16 MB (reused as vT)
    bf16_t* pb   = (bf16_t*)carve((size_t)NB * NTP * NC * 2);       // 1 MB  (reused as pvT)
    bf16_t* wTa  = (bf16_t*)carve((size_t)3 * NC * NC * 2);         // 6 MB
    bf16_t* wTp  = (bf16_t*)carve((size_t)3 * NC * NC * 2);         // 6 MB
    bf16_t* wTpr = (bf16_t*)carve((size_t)NC * NC * 2);             // 2 MB
    bf16_t* qkv  = (bf16_t*)carve((size_t)NB * NT * 3 * NC * 2);    // 48 MB
    bf16_t* pqkv = (bf16_t*)carve((size_t)NB * NTP * 3 * NC * 2);   // 3 MB
    bf16_t* yb   = (bf16_t*)carve((size_t)NB * NT * NC * 2);        // 16 MB

    // casts
    k_cast_bf16<<<(NB * NT * NC / 4 + 255) / 256, 256, 0, stream>>>(x, xb, NB * NT * NC / 4);
    k_cast_bf16<<<(NB * NTP * NC / 4 + 255) / 256, 256, 0, stream>>>(prefix, pb, NB * NTP * NC / 4);
    // weight transposes (to B^T bf16 layout)
    k_transpose_cast<<<dim3(3 * NC / 32, NC / 32), 256, 0, stream>>>(w_attn, wTa, NC, 3 * NC);
    k_transpose_cast<<<dim3(3 * NC / 32, NC / 32), 256, 0, stream>>>(w_prefix, wTp, NC, 3 * NC);
    k_transpose_cast<<<dim3(NC / 32, NC / 32), 256, 0, stream>>>(w_proj, wTpr, NC, NC);
    // qkv = x @ w_attn + b_attn  (bf16 out)
    k_gemm_bt<false><<<dim3(3 * NC / 128, NB * NT / 128), 256, 0, stream>>>(
        xb, wTa, b_attn, qkv, NB * NT, 3 * NC, NC);
    // pqkv = prefix @ w_prefix + b_prefix (bf16 out)
    k_gemm_bt<false><<<dim3(3 * NC / 128, NB * NTP / 128), 256, 0, stream>>>(
        pb, wTp, b_prefix, pqkv, NB * NTP, 3 * NC, NC);
    // per-head V transposes (xb/pb are dead now; reuse as vT/pvT)
    bf16_t* vT  = xb;   // (b,h,d,1024) = 16 MB
    bf16_t* pvT = pb;   // (b,h,d,64)   = 1 MB
    k_vT<<<dim3(NT / 32, ND / 32, NB * NH), 256, 0, stream>>>(qkv, vT, NT);
    k_vT<<<dim3(NTP / 32, ND / 32, NB * NH), 256, 0, stream>>>(pqkv, pvT, NTP);
    // attention (barrier-free)
    k_attn2<<<dim3(NT / 64, NH, NB), 256, 0, stream>>>(qkv, pqkv, vT, pvT, yb);
    // out = y @ w_proj + b_proj (fp32 out)
    k_gemm_bt<true><<<dim3(NC / 128, NB * NT / 128), 256, 0, stream>>>(
        yb, wTpr, b_proj, out, NB * NT, NC, NC);
}